// Round 23
// baseline (138.751 us; speedup 1.0000x reference)
//
#include <hip/hip_runtime.h>
#include <hip/hip_cooperative_groups.h>

namespace cg = cooperative_groups;

#define BB 4
#define TT 512
#define SS 512
#define DD 128
#define HID 64

typedef _Float16 f16;
typedef f16 f16x4 __attribute__((ext_vector_type(4)));
typedef f16 f16x8 __attribute__((ext_vector_type(8)));
typedef float f32x4 __attribute__((ext_vector_type(4)));

#define SPLAT8(c) ((f16x8){(f16)(c),(f16)(c),(f16)(c),(f16)(c),(f16)(c),(f16)(c),(f16)(c),(f16)(c)})

// gelu from half-argument: input xh = x/2, output gelu(x) = xh + v*P(v),
// v = xh^2 = x^2/4. Quintic P, f16-normal coeffs. Data |x| < 3 (fit range).
__device__ __forceinline__ f16x8 gelu_h(f16x8 xh) {
    f16x8 v = xh * xh;
    f16x8 p = __builtin_elementwise_fma(v, SPLAT8(-7.84424e-3f), SPLAT8(6.836736e-2f));
    p = __builtin_elementwise_fma(p, v, SPLAT8(-2.6470144e-1f));
    p = __builtin_elementwise_fma(p, v, SPLAT8(6.286528e-1f));
    p = __builtin_elementwise_fma(p, v, SPLAT8(-1.0660912f));
    p = __builtin_elementwise_fma(p, v, SPLAT8(1.596200f));
    return __builtin_elementwise_fma(v, p, xh);
}

#define LOADKV(KV0, KV1, CHUNK) {                                         \
    const f16* p_ = pkbase + (size_t)(CHUNK) * 16 * HID;                  \
    (KV0) = *(const f16x8*)(p_);                                          \
    (KV1) = *(const f16x8*)(p_ + 32); }

#define STAGE1(KV0, KV1) {                                                \
    a0 = gelu_h(__builtin_elementwise_fma((KV0), SPLAT8(0.5f), pqh0));    \
    a1 = gelu_h(__builtin_elementwise_fma((KV1), SPLAT8(0.5f), pqh1)); }

#define DOMFMA(ACC) {                                                     \
    _Pragma("unroll")                                                     \
    for (int nb = 0; nb < 4; ++nb) {                                      \
        ACC[nb] = __builtin_amdgcn_mfma_f32_16x16x32_f16(bw[0][nb], a0, Z4, 0, 0, 0); \
        ACC[nb] = __builtin_amdgcn_mfma_f32_16x16x32_f16(bw[1][nb], a1, ACC[nb], 0, 0, 0); \
    } }

#define STAGE2(ACC, C) {                                                  \
    f16x8 z0, z1;                                                         \
    _Pragma("unroll")                                                     \
    for (int i = 0; i < 8; ++i) {                                         \
        z0[i] = (f16)ACC[i >> 2][i & 3];                                  \
        z1[i] = (f16)ACC[2 + (i >> 2)][i & 3];                            \
    }                                                                     \
    z0 = z0 * (z0 + betaA0);                                              \
    z1 = z1 * (z1 + betaA1);                                              \
    f32x4 accQ = __builtin_amdgcn_mfma_f32_16x16x32_f16(w3qA0, z0, Z4, 0, 0, 0); \
    accQ = __builtin_amdgcn_mfma_f32_16x16x32_f16(w3qA1, z1, accQ, 0, 0, 0); \
    if (lane < 16) orow[(C) * 16 + lane] = accQ[0] + clv; }

// Single cooperative kernel:
//  phase 1: units 0..63 pqk (LDS-staged W1c, 4 waves x 16 rows each);
//           units 64..71 w2f frag-pack; unit 72 w3q/betaq/clv.
//  grid.sync()
//  phase 2: main, grid-stride over 4096 (t, 256s) wave-units.
__global__ __launch_bounds__(256, 4) void fused_kernel(
    const float* __restrict__ h, const float* __restrict__ h_src,
    const float* __restrict__ W1, const float* __restrict__ b1,
    const float* __restrict__ W2, const float* __restrict__ b2,
    const float* __restrict__ W3, const float* __restrict__ b3,
    f16* __restrict__ pq, f16* __restrict__ pk,
    f16* __restrict__ w2f, f16* __restrict__ w3q,
    f16* __restrict__ betaq, float* __restrict__ clvp,
    float* __restrict__ out)
{
    __shared__ f16 w1t[64 * 136];               // [h][d], d padded to 136
    const int tid  = threadIdx.x;
    const int wave = tid >> 6;
    const int lane = tid & 63;
    const int g = lane >> 4;
    const int r = lane & 15;
    const int nblocks = gridDim.x;

    // ======== phase 1 ========
    for (int unit = blockIdx.x; unit < 73; unit += nblocks) {
        if (unit < 64) {
            // pqk: 64 rows per unit (4 waves x 16)
            const int half = unit >> 5;
            const int rowb = (unit & 31) * 64;
            const float* src = half ? h_src : h;        // [2048][128]
            const float* Wa  = W1 + (size_t)half * DD * HID;
            const float* Wd  = W1 + (size_t)2 * DD * HID;
            const float  sgn = half ? -1.0f : 1.0f;
            f16* dst = half ? pk : pq;

            for (int j = tid; j < DD * HID; j += 256) {
                const int d  = j >> 6;
                const int hh = j & 63;
                w1t[hh * 136 + d] = (f16)fmaf(sgn, Wd[j], Wa[j]);
            }
            __syncthreads();

            const int row0 = rowb + wave * 16;
            f16x8 bx[4];
            const float* srow = src + (size_t)(row0 + r) * DD + g * 8;
            #pragma unroll
            for (int ks = 0; ks < 4; ++ks) {
                float4 q0 = *(const float4*)(srow + ks * 32);
                float4 q1 = *(const float4*)(srow + ks * 32 + 4);
                f16x8 v;
                v[0] = (f16)q0.x; v[1] = (f16)q0.y; v[2] = (f16)q0.z; v[3] = (f16)q0.w;
                v[4] = (f16)q1.x; v[5] = (f16)q1.y; v[6] = (f16)q1.z; v[7] = (f16)q1.w;
                bx[ks] = v;
            }

            #pragma unroll
            for (int nb = 0; nb < 4; ++nb) {
                f32x4 acc;
                if (half == 0) {
                    float4 bv = *(const float4*)(b1 + nb * 16 + g * 4);
                    acc = (f32x4){bv.x, bv.y, bv.z, bv.w};
                } else {
                    acc = (f32x4){0.f, 0.f, 0.f, 0.f};
                }
                const f16* wrow = &w1t[(nb * 16 + r) * 136];
                #pragma unroll
                for (int ks = 0; ks < 4; ++ks) {
                    f16x8 aw = *(const f16x8*)(wrow + ks * 32 + g * 8);
                    acc = __builtin_amdgcn_mfma_f32_16x16x32_f16(aw, bx[ks], acc, 0, 0, 0);
                }
                f16x4 w;
                w[0] = (f16)acc[0]; w[1] = (f16)acc[1];
                w[2] = (f16)acc[2]; w[3] = (f16)acc[3];
                *(f16x4*)(dst + (size_t)(row0 + r) * HID + nb * 16 + g * 4) = w;
            }
            __syncthreads();
        } else if (unit < 72) {
            // w2f frag-pack: 512 elems per unit
            #pragma unroll
            for (int k2 = 0; k2 < 2; ++k2) {
                const int idx  = (unit - 64) * 512 + k2 * 256 + tid;
                const int kh   = idx >> 11;
                const int nb   = (idx >> 9) & 3;
                const int ln   = (idx >> 3) & 63;
                const int i    = idx & 7;
                const int k    = kh * 32 + (ln >> 4) * 8 + i;
                const int n    = nb * 16 + (ln & 15);
                w2f[idx] = (f16)W2[k * HID + n];
            }
        } else {
            // quad-path constants
            if (tid < HID) {
                const int kh2 = tid >> 5, rem = tid & 31;
                const int gg  = rem >> 3, ii = rem & 7;
                const int n   = (kh2 * 2 + (ii >> 2)) * 16 + gg * 4 + (ii & 3);
                w3q[tid]   = (f16)(0.39894228f * W3[n]);
                betaq[tid] = (f16)fmaf(2.0f, b2[n], 1.25331414f);
            } else if (tid == HID) {
                float cl = b3[0];
                for (int n = 0; n < HID; ++n)
                    cl = fmaf(W3[n], fmaf(0.39894228f * b2[n], b2[n], 0.5f * b2[n]), cl);
                clvp[0] = cl;
            }
        }
    }

    __threadfence();                 // device-scope visibility across XCDs
    cg::this_grid().sync();

    // ======== phase 2: main ========
    f16x8 bw[2][4];
    #pragma unroll
    for (int kh = 0; kh < 2; ++kh)
        #pragma unroll
        for (int nb = 0; nb < 4; ++nb)
            bw[kh][nb] = *(const f16x8*)(w2f + ((kh * 4 + nb) * 64 + lane) * 8);

    f16x8 w3qA0  = *(const f16x8*)(w3q + g * 8);
    f16x8 w3qA1  = *(const f16x8*)(w3q + 32 + g * 8);
    f16x8 betaA0 = *(const f16x8*)(betaq + g * 8);
    f16x8 betaA1 = *(const f16x8*)(betaq + 32 + g * 8);
    const float clv = clvp[0];
    const f32x4 Z4 = {0.f, 0.f, 0.f, 0.f};

    const int nwaves = nblocks * 4;
    for (int wu = blockIdx.x * 4 + wave; wu < 4096; wu += nwaves) {
        const int bt  = wu >> 1;
        const int sb0 = (wu & 1) * 256;
        const int b   = bt >> 9;

        const f16* pqrow = pq + (size_t)bt * HID + g * 8;
        f16x8 pqh0 = (*(const f16x8*)(pqrow)) * SPLAT8(0.5f);
        f16x8 pqh1 = (*(const f16x8*)(pqrow + 32)) * SPLAT8(0.5f);

        const f16* pkbase = pk + ((size_t)b * SS + sb0 + r) * HID + g * 8;
        float* orow = out + (size_t)bt * SS + sb0;

        f16x8 kvA0, kvA1, kvB0, kvB1;
        f16x8 a0, a1;
        f32x4 acc[4];

        LOADKV(kvA0, kvA1, 0)
        LOADKV(kvB0, kvB1, 1)
        STAGE1(kvA0, kvA1)

        #pragma unroll
        for (int cc = 0; cc < 8; ++cc) {
            DOMFMA(acc)
            if (cc < 7) LOADKV(kvA0, kvA1, 2 * cc + 2)
            STAGE1(kvB0, kvB1)
            STAGE2(acc, 2 * cc)

            DOMFMA(acc)
            if (cc < 7) {
                LOADKV(kvB0, kvB1, 2 * cc + 3)
                STAGE1(kvA0, kvA1)
            }
            STAGE2(acc, 2 * cc + 1)
        }
    }
}

extern "C" void kernel_launch(void* const* d_in, const int* in_sizes, int n_in,
                              void* d_out, int out_size, void* d_ws, size_t ws_size,
                              hipStream_t stream) {
    const float* h     = (const float*)d_in[0];
    const float* h_src = (const float*)d_in[1];
    const float* W1    = (const float*)d_in[2];
    const float* b1    = (const float*)d_in[3];
    const float* W2    = (const float*)d_in[4];
    const float* b2    = (const float*)d_in[5];
    const float* W3    = (const float*)d_in[6];
    const float* b3    = (const float*)d_in[7];
    float* out = (float*)d_out;

    f16* pq    = (f16*)d_ws;                     // B*T*HID f16
    f16* pk    = pq + (size_t)BB * TT * HID;     // B*S*HID f16
    f16* w2f   = pk + (size_t)BB * SS * HID;     // 4096 f16
    f16* w3q   = w2f + HID * HID;                // 64 f16
    f16* betaq = w3q + HID;                      // 64 f16
    float* clvp = (float*)(betaq + HID);         // 1 f32

    // ONE cooperative launch (saves ~5.5-7us of per-launch overhead).
    // Grid sized to guaranteed co-residency (pure occupancy query).
    int maxb = 0;
    hipOccupancyMaxActiveBlocksPerMultiprocessor(&maxb, fused_kernel, 256, 0);
    int grid = maxb * 256;
    if (grid > 1024) grid = 1024;
    if (grid < 128) grid = 128;

    void* args[] = {(void*)&h, (void*)&h_src, (void*)&W1, (void*)&b1,
                    (void*)&W2, (void*)&b2, (void*)&W3, (void*)&b3,
                    (void*)&pq, (void*)&pk, (void*)&w2f, (void*)&w3q,
                    (void*)&betaq, (void*)&clvp, (void*)&out};
    hipLaunchCooperativeKernel(fused_kernel, dim3(grid), dim3(256),
                               args, 0, stream);
}

// Round 24
// 33.053 us; speedup vs baseline: 4.1978x; 4.1978x over previous
//
#include <hip/hip_runtime.h>

#define BB 4
#define TT 512
#define SS 512
#define DD 128
#define HID 64

typedef _Float16 f16;
typedef f16 f16x4 __attribute__((ext_vector_type(4)));
typedef f16 f16x8 __attribute__((ext_vector_type(8)));
typedef __fp16 h16x2 __attribute__((ext_vector_type(2)));
typedef float f32x4 __attribute__((ext_vector_type(4)));

#define SPLAT8(c) ((f16x8){(f16)(c),(f16)(c),(f16)(c),(f16)(c),(f16)(c),(f16)(c),(f16)(c),(f16)(c)})

// gelu from half-argument: input xh = x/2, output gelu(x) = xh + v*P(v),
// v = xh^2 = x^2/4. Quintic P, f16-normal coeffs. Data |x| < 3 (fit range).
__device__ __forceinline__ f16x8 gelu_h(f16x8 xh) {
    f16x8 v = xh * xh;
    f16x8 p = __builtin_elementwise_fma(v, SPLAT8(-7.84424e-3f), SPLAT8(6.836736e-2f));
    p = __builtin_elementwise_fma(p, v, SPLAT8(-2.6470144e-1f));
    p = __builtin_elementwise_fma(p, v, SPLAT8(6.286528e-1f));
    p = __builtin_elementwise_fma(p, v, SPLAT8(-1.0660912f));
    p = __builtin_elementwise_fma(p, v, SPLAT8(1.596200f));
    return __builtin_elementwise_fma(v, p, xh);
}

// setup (R22, unchanged): ONE launch does weights-prep (aux block) AND pqk.
__global__ __launch_bounds__(128) void setup_kernel(
    const float* __restrict__ h, const float* __restrict__ h_src,
    const float* __restrict__ W1, const float* __restrict__ b1,
    const float* __restrict__ W2, const float* __restrict__ b2,
    const float* __restrict__ W3, const float* __restrict__ b3,
    f16* __restrict__ pq, f16* __restrict__ pk,
    f16* __restrict__ w2f, f16* __restrict__ w3q,
    f16* __restrict__ betaq, float* __restrict__ clvp)
{
    const int tid = threadIdx.x;
    const int bid = blockIdx.x;

    if (bid == 128) {                           // aux block: weight transforms
        for (int idx = tid; idx < 4096; idx += 128) {
            const int kh   = idx >> 11;
            const int nb   = (idx >> 9) & 3;
            const int lane = (idx >> 3) & 63;
            const int i    = idx & 7;
            const int k    = kh * 32 + (lane >> 4) * 8 + i;
            const int n    = nb * 16 + (lane & 15);
            w2f[idx] = (f16)W2[k * HID + n];
        }
        if (tid < HID) {
            const int kh2 = tid >> 5, rem = tid & 31;
            const int gg  = rem >> 3, ii = rem & 7;
            const int n   = (kh2 * 2 + (ii >> 2)) * 16 + gg * 4 + (ii & 3);
            w3q[tid]   = (f16)(0.39894228f * W3[n]);
            betaq[tid] = (f16)fmaf(2.0f, b2[n], 1.25331414f);
        } else if (tid == HID) {
            float cl = b3[0];
            for (int n = 0; n < HID; ++n)
                cl = fmaf(W3[n], fmaf(0.39894228f * b2[n], b2[n], 0.5f * b2[n]), cl);
            clvp[0] = cl;
        }
        return;
    }

    // ---- pqk blocks: 0..63 -> pq, 64..127 -> pk; 32 rows per block ----
    __shared__ f16 w1t[64 * 136];               // [h][d], d-dim padded to 136

    const int half = bid >> 6;
    const int rowb = (bid & 63) * 32;
    const float* src = half ? h_src : h;        // [2048][128]
    const float* Wa  = W1 + (size_t)half * DD * HID;
    const float* Wd  = W1 + (size_t)2 * DD * HID;
    const float  sgn = half ? -1.0f : 1.0f;
    f16* dst = half ? pk : pq;

    for (int j = tid; j < DD * HID; j += 128) {
        const int d  = j >> 6;
        const int hh = j & 63;
        w1t[hh * 136 + d] = (f16)fmaf(sgn, Wd[j], Wa[j]);
    }
    __syncthreads();

    const int wave = tid >> 6;
    const int lane = tid & 63;
    const int g = lane >> 4;
    const int r = lane & 15;
    const int row0 = rowb + wave * 16;

    f16x8 bx[4];
    const float* srow = src + (size_t)(row0 + r) * DD + g * 8;
    #pragma unroll
    for (int ks = 0; ks < 4; ++ks) {
        float4 q0 = *(const float4*)(srow + ks * 32);
        float4 q1 = *(const float4*)(srow + ks * 32 + 4);
        f16x8 v;
        v[0] = (f16)q0.x; v[1] = (f16)q0.y; v[2] = (f16)q0.z; v[3] = (f16)q0.w;
        v[4] = (f16)q1.x; v[5] = (f16)q1.y; v[6] = (f16)q1.z; v[7] = (f16)q1.w;
        bx[ks] = v;
    }

    #pragma unroll
    for (int nb = 0; nb < 4; ++nb) {
        f32x4 acc;
        if (half == 0) {
            float4 bv = *(const float4*)(b1 + nb * 16 + g * 4);
            acc = (f32x4){bv.x, bv.y, bv.z, bv.w};
        } else {
            acc = (f32x4){0.f, 0.f, 0.f, 0.f};
        }
        const f16* wrow = &w1t[(nb * 16 + r) * 136];
        #pragma unroll
        for (int ks = 0; ks < 4; ++ks) {
            f16x8 aw = *(const f16x8*)(wrow + ks * 32 + g * 8);
            acc = __builtin_amdgcn_mfma_f32_16x16x32_f16(aw, bx[ks], acc, 0, 0, 0);
        }
        f16x4 w;
        w[0] = (f16)acc[0]; w[1] = (f16)acc[1];
        w[2] = (f16)acc[2]; w[3] = (f16)acc[3];
        *(f16x4*)(dst + (size_t)(row0 + r) * HID + nb * 16 + g * 4) = w;
    }
}

#define LOADKV(KV0, KV1, CHUNK) {                                         \
    const f16* p_ = pkbase + (size_t)(CHUNK) * 16 * HID;                  \
    (KV0) = *(const f16x8*)(p_);                                          \
    (KV1) = *(const f16x8*)(p_ + 32); }

#define STAGE1(KV0, KV1) {                                                \
    a0 = gelu_h(__builtin_elementwise_fma((KV0), SPLAT8(0.5f), pqh0));    \
    a1 = gelu_h(__builtin_elementwise_fma((KV1), SPLAT8(0.5f), pqh1)); }

#define DOMFMA(ACC) {                                                     \
    _Pragma("unroll")                                                     \
    for (int nb = 0; nb < 4; ++nb) {                                      \
        ACC[nb] = __builtin_amdgcn_mfma_f32_16x16x32_f16(bw[0][nb], a0, Z4, 0, 0, 0); \
        ACC[nb] = __builtin_amdgcn_mfma_f32_16x16x32_f16(bw[1][nb], a1, ACC[nb], 0, 0, 0); \
    } }

// stage-2 on the matrix pipe; packed f32->f16 conversion via cvt_pkrtz
// (8 instrs vs 16 scalar cvts; |z|<=0.25 so RTZ delta <= 2^-13 rel).
#define STAGE2(ACC, C) {                                                  \
    union { h16x2 q[4]; f16x8 v; } uz0, uz1;                              \
    uz0.q[0] = __builtin_amdgcn_cvt_pkrtz(ACC[0][0], ACC[0][1]);          \
    uz0.q[1] = __builtin_amdgcn_cvt_pkrtz(ACC[0][2], ACC[0][3]);          \
    uz0.q[2] = __builtin_amdgcn_cvt_pkrtz(ACC[1][0], ACC[1][1]);          \
    uz0.q[3] = __builtin_amdgcn_cvt_pkrtz(ACC[1][2], ACC[1][3]);          \
    uz1.q[0] = __builtin_amdgcn_cvt_pkrtz(ACC[2][0], ACC[2][1]);          \
    uz1.q[1] = __builtin_amdgcn_cvt_pkrtz(ACC[2][2], ACC[2][3]);          \
    uz1.q[2] = __builtin_amdgcn_cvt_pkrtz(ACC[3][0], ACC[3][1]);          \
    uz1.q[3] = __builtin_amdgcn_cvt_pkrtz(ACC[3][2], ACC[3][3]);          \
    f16x8 z0 = uz0.v, z1 = uz1.v;                                         \
    z0 = z0 * (z0 + betaA0);                                              \
    z1 = z1 * (z1 + betaA1);                                              \
    f32x4 accQ = __builtin_amdgcn_mfma_f32_16x16x32_f16(w3qA0, z0, Z4, 0, 0, 0); \
    accQ = __builtin_amdgcn_mfma_f32_16x16x32_f16(w3qA1, z1, accQ, 0, 0, 0); \
    if (lane < 16) orow[(C) * 16 + lane] = accQ[0] + clv; }

// R18 geometry: one wave = (t, 256 s), 16 chunks, 4096 waves.
// __launch_bounds__(256,5): cap combined regs at 102 -> 5 waves/SIMD
// (25% more TLP against the ~50% issue-stall). Fork: if this spills,
// expect a regression and revert to 4 next round.
__global__ __launch_bounds__(256, 5) void main_kernel(
    const f16* __restrict__ pq, const f16* __restrict__ pk,
    const f16* __restrict__ w2f,
    const f16* __restrict__ w3q, const f16* __restrict__ betaq,
    const float* __restrict__ clvp, float* __restrict__ out)
{
    const int tid  = threadIdx.x;
    const int wave = tid >> 6;
    const int lane = tid & 63;
    const int g = lane >> 4;   // k-group / n-row-group
    const int r = lane & 15;   // A-n / B-pair

    const int wu  = blockIdx.x * 4 + wave;   // 0..4095
    const int bt  = wu >> 1;
    const int sb0 = (wu & 1) * 256;
    const int b   = bt >> 9;

    f16x8 bw[2][4];
    #pragma unroll
    for (int kh = 0; kh < 2; ++kh)
        #pragma unroll
        for (int nb = 0; nb < 4; ++nb)
            bw[kh][nb] = *(const f16x8*)(w2f + ((kh * 4 + nb) * 64 + lane) * 8);

    const f16* pqrow = pq + (size_t)bt * HID + g * 8;
    f16x8 pqh0 = (*(const f16x8*)(pqrow)) * SPLAT8(0.5f);
    f16x8 pqh1 = (*(const f16x8*)(pqrow + 32)) * SPLAT8(0.5f);

    f16x8 w3qA0  = *(const f16x8*)(w3q + g * 8);
    f16x8 w3qA1  = *(const f16x8*)(w3q + 32 + g * 8);
    f16x8 betaA0 = *(const f16x8*)(betaq + g * 8);
    f16x8 betaA1 = *(const f16x8*)(betaq + 32 + g * 8);

    const float clv = clvp[0];
    const f32x4 Z4 = {0.f, 0.f, 0.f, 0.f};

    const f16* pkbase = pk + ((size_t)b * SS + sb0 + r) * HID + g * 8;
    float* orow = out + (size_t)bt * SS + sb0;

    f16x8 kvA0, kvA1, kvB0, kvB1;
    f16x8 a0, a1;
    f32x4 acc[4];

    LOADKV(kvA0, kvA1, 0)
    LOADKV(kvB0, kvB1, 1)
    STAGE1(kvA0, kvA1)                // chunk 0 frags in a0,a1

    #pragma unroll
    for (int cc = 0; cc < 8; ++cc) {
        DOMFMA(acc)
        if (cc < 7) LOADKV(kvA0, kvA1, 2 * cc + 2)
        STAGE1(kvB0, kvB1)
        STAGE2(acc, 2 * cc)

        DOMFMA(acc)
        if (cc < 7) {
            LOADKV(kvB0, kvB1, 2 * cc + 3)
            STAGE1(kvA0, kvA1)
        }
        STAGE2(acc, 2 * cc + 1)
    }
}

extern "C" void kernel_launch(void* const* d_in, const int* in_sizes, int n_in,
                              void* d_out, int out_size, void* d_ws, size_t ws_size,
                              hipStream_t stream) {
    const float* h     = (const float*)d_in[0];
    const float* h_src = (const float*)d_in[1];
    const float* W1    = (const float*)d_in[2];
    const float* b1    = (const float*)d_in[3];
    const float* W2    = (const float*)d_in[4];
    const float* b2    = (const float*)d_in[5];
    const float* W3    = (const float*)d_in[6];
    const float* b3    = (const float*)d_in[7];
    float* out = (float*)d_out;

    f16* pq    = (f16*)d_ws;                     // B*T*HID f16
    f16* pk    = pq + (size_t)BB * TT * HID;     // B*S*HID f16
    f16* w2f   = pk + (size_t)BB * SS * HID;     // 4096 f16
    f16* w3q   = w2f + HID * HID;                // 64 f16
    f16* betaq = w3q + HID;                      // 64 f16
    float* clvp = (float*)(betaq + HID);         // 1 f32

    // TWO launches (cooperative fusion falsified in R23: grid.sync ~190us).
    setup_kernel<<<129, 128, 0, stream>>>(h, h_src, W1, b1, W2, b2, W3, b3,
                                          pq, pk, w2f, w3q, betaq, clvp);
    main_kernel<<<1024, 256, 0, stream>>>(pq, pk, w2f, w3q, betaq, clvp, out);
}

// Round 25
// 29.125 us; speedup vs baseline: 4.7639x; 1.1349x over previous
//
#include <hip/hip_runtime.h>

#define BB 4
#define TT 512
#define SS 512
#define DD 128
#define HID 64

typedef _Float16 f16;
typedef f16 f16x4 __attribute__((ext_vector_type(4)));
typedef f16 f16x8 __attribute__((ext_vector_type(8)));
typedef __fp16 h16x2 __attribute__((ext_vector_type(2)));
typedef float f32x4 __attribute__((ext_vector_type(4)));

#define SPLAT8(c) ((f16x8){(f16)(c),(f16)(c),(f16)(c),(f16)(c),(f16)(c),(f16)(c),(f16)(c),(f16)(c)})

// gelu from half-argument: input xh = x/2, output gelu(x) = xh + v*P(v),
// v = xh^2 = x^2/4. Quintic P, f16-normal coeffs. Data |x| < 3 (fit range).
__device__ __forceinline__ f16x8 gelu_h(f16x8 xh) {
    f16x8 v = xh * xh;
    f16x8 p = __builtin_elementwise_fma(v, SPLAT8(-7.84424e-3f), SPLAT8(6.836736e-2f));
    p = __builtin_elementwise_fma(p, v, SPLAT8(-2.6470144e-1f));
    p = __builtin_elementwise_fma(p, v, SPLAT8(6.286528e-1f));
    p = __builtin_elementwise_fma(p, v, SPLAT8(-1.0660912f));
    p = __builtin_elementwise_fma(p, v, SPLAT8(1.596200f));
    return __builtin_elementwise_fma(v, p, xh);
}

// setup (R22, unchanged): ONE launch does weights-prep (aux block) AND pqk.
__global__ __launch_bounds__(128) void setup_kernel(
    const float* __restrict__ h, const float* __restrict__ h_src,
    const float* __restrict__ W1, const float* __restrict__ b1,
    const float* __restrict__ W2, const float* __restrict__ b2,
    const float* __restrict__ W3, const float* __restrict__ b3,
    f16* __restrict__ pq, f16* __restrict__ pk,
    f16* __restrict__ w2f, f16* __restrict__ w3q,
    f16* __restrict__ betaq, float* __restrict__ clvp)
{
    const int tid = threadIdx.x;
    const int bid = blockIdx.x;

    if (bid == 128) {                           // aux block: weight transforms
        for (int idx = tid; idx < 4096; idx += 128) {
            const int kh   = idx >> 11;
            const int nb   = (idx >> 9) & 3;
            const int lane = (idx >> 3) & 63;
            const int i    = idx & 7;
            const int k    = kh * 32 + (lane >> 4) * 8 + i;
            const int n    = nb * 16 + (lane & 15);
            w2f[idx] = (f16)W2[k * HID + n];
        }
        if (tid < HID) {
            const int kh2 = tid >> 5, rem = tid & 31;
            const int gg  = rem >> 3, ii = rem & 7;
            const int n   = (kh2 * 2 + (ii >> 2)) * 16 + gg * 4 + (ii & 3);
            w3q[tid]   = (f16)(0.39894228f * W3[n]);
            betaq[tid] = (f16)fmaf(2.0f, b2[n], 1.25331414f);
        } else if (tid == HID) {
            float cl = b3[0];
            for (int n = 0; n < HID; ++n)
                cl = fmaf(W3[n], fmaf(0.39894228f * b2[n], b2[n], 0.5f * b2[n]), cl);
            clvp[0] = cl;
        }
        return;
    }

    // ---- pqk blocks: 0..63 -> pq, 64..127 -> pk; 32 rows per block ----
    __shared__ f16 w1t[64 * 136];               // [h][d], d-dim padded to 136

    const int half = bid >> 6;
    const int rowb = (bid & 63) * 32;
    const float* src = half ? h_src : h;        // [2048][128]
    const float* Wa  = W1 + (size_t)half * DD * HID;
    const float* Wd  = W1 + (size_t)2 * DD * HID;
    const float  sgn = half ? -1.0f : 1.0f;
    f16* dst = half ? pk : pq;

    for (int j = tid; j < DD * HID; j += 128) {
        const int d  = j >> 6;
        const int hh = j & 63;
        w1t[hh * 136 + d] = (f16)fmaf(sgn, Wd[j], Wa[j]);
    }
    __syncthreads();

    const int wave = tid >> 6;
    const int lane = tid & 63;
    const int g = lane >> 4;
    const int r = lane & 15;
    const int row0 = rowb + wave * 16;

    f16x8 bx[4];
    const float* srow = src + (size_t)(row0 + r) * DD + g * 8;
    #pragma unroll
    for (int ks = 0; ks < 4; ++ks) {
        float4 q0 = *(const float4*)(srow + ks * 32);
        float4 q1 = *(const float4*)(srow + ks * 32 + 4);
        f16x8 v;
        v[0] = (f16)q0.x; v[1] = (f16)q0.y; v[2] = (f16)q0.z; v[3] = (f16)q0.w;
        v[4] = (f16)q1.x; v[5] = (f16)q1.y; v[6] = (f16)q1.z; v[7] = (f16)q1.w;
        bx[ks] = v;
    }

    #pragma unroll
    for (int nb = 0; nb < 4; ++nb) {
        f32x4 acc;
        if (half == 0) {
            float4 bv = *(const float4*)(b1 + nb * 16 + g * 4);
            acc = (f32x4){bv.x, bv.y, bv.z, bv.w};
        } else {
            acc = (f32x4){0.f, 0.f, 0.f, 0.f};
        }
        const f16* wrow = &w1t[(nb * 16 + r) * 136];
        #pragma unroll
        for (int ks = 0; ks < 4; ++ks) {
            f16x8 aw = *(const f16x8*)(wrow + ks * 32 + g * 8);
            acc = __builtin_amdgcn_mfma_f32_16x16x32_f16(aw, bx[ks], acc, 0, 0, 0);
        }
        f16x4 w;
        w[0] = (f16)acc[0]; w[1] = (f16)acc[1];
        w[2] = (f16)acc[2]; w[3] = (f16)acc[3];
        *(f16x4*)(dst + (size_t)(row0 + r) * HID + nb * 16 + g * 4) = w;
    }
}

#define LOADKV(KV0, KV1, CHUNK) {                                         \
    const f16* p_ = pkbase + (size_t)(CHUNK) * 16 * HID;                  \
    (KV0) = *(const f16x8*)(p_);                                          \
    (KV1) = *(const f16x8*)(p_ + 32); }

#define STAGE1(KV0, KV1) {                                                \
    a0 = gelu_h(__builtin_elementwise_fma((KV0), SPLAT8(0.5f), pqh0));    \
    a1 = gelu_h(__builtin_elementwise_fma((KV1), SPLAT8(0.5f), pqh1)); }

#define DOMFMA(ACC) {                                                     \
    _Pragma("unroll")                                                     \
    for (int nb = 0; nb < 4; ++nb) {                                      \
        ACC[nb] = __builtin_amdgcn_mfma_f32_16x16x32_f16(bw[0][nb], a0, Z4, 0, 0, 0); \
        ACC[nb] = __builtin_amdgcn_mfma_f32_16x16x32_f16(bw[1][nb], a1, ACC[nb], 0, 0, 0); \
    } }

// stage-2 on the matrix pipe; packed f32->f16 conversion via cvt_pkrtz
// (8 instrs vs 16 scalar cvts; |z|<=0.25 so RTZ delta <= 2^-13 rel).
#define STAGE2(ACC, C) {                                                  \
    union { h16x2 q[4]; f16x8 v; } uz0, uz1;                              \
    uz0.q[0] = __builtin_amdgcn_cvt_pkrtz(ACC[0][0], ACC[0][1]);          \
    uz0.q[1] = __builtin_amdgcn_cvt_pkrtz(ACC[0][2], ACC[0][3]);          \
    uz0.q[2] = __builtin_amdgcn_cvt_pkrtz(ACC[1][0], ACC[1][1]);          \
    uz0.q[3] = __builtin_amdgcn_cvt_pkrtz(ACC[1][2], ACC[1][3]);          \
    uz1.q[0] = __builtin_amdgcn_cvt_pkrtz(ACC[2][0], ACC[2][1]);          \
    uz1.q[1] = __builtin_amdgcn_cvt_pkrtz(ACC[2][2], ACC[2][3]);          \
    uz1.q[2] = __builtin_amdgcn_cvt_pkrtz(ACC[3][0], ACC[3][1]);          \
    uz1.q[3] = __builtin_amdgcn_cvt_pkrtz(ACC[3][2], ACC[3][3]);          \
    f16x8 z0 = uz0.v, z1 = uz1.v;                                         \
    z0 = z0 * (z0 + betaA0);                                              \
    z1 = z1 * (z1 + betaA1);                                              \
    f32x4 accQ = __builtin_amdgcn_mfma_f32_16x16x32_f16(w3qA0, z0, Z4, 0, 0, 0); \
    accQ = __builtin_amdgcn_mfma_f32_16x16x32_f16(w3qA1, z1, accQ, 0, 0, 0); \
    if (lane < 16) orow[(C) * 16 + lane] = accQ[0] + clv; }

// R18/R22 geometry (best known): one wave = (t, 256 s), 16 chunks,
// 4096 waves, __launch_bounds__(256,4) — (256,5) falsified in R24 (spills).
__global__ __launch_bounds__(256, 4) void main_kernel(
    const f16* __restrict__ pq, const f16* __restrict__ pk,
    const f16* __restrict__ w2f,
    const f16* __restrict__ w3q, const f16* __restrict__ betaq,
    const float* __restrict__ clvp, float* __restrict__ out)
{
    const int tid  = threadIdx.x;
    const int wave = tid >> 6;
    const int lane = tid & 63;
    const int g = lane >> 4;   // k-group / n-row-group
    const int r = lane & 15;   // A-n / B-pair

    const int wu  = blockIdx.x * 4 + wave;   // 0..4095
    const int bt  = wu >> 1;
    const int sb0 = (wu & 1) * 256;
    const int b   = bt >> 9;

    f16x8 bw[2][4];
    #pragma unroll
    for (int kh = 0; kh < 2; ++kh)
        #pragma unroll
        for (int nb = 0; nb < 4; ++nb)
            bw[kh][nb] = *(const f16x8*)(w2f + ((kh * 4 + nb) * 64 + lane) * 8);

    const f16* pqrow = pq + (size_t)bt * HID + g * 8;
    f16x8 pqh0 = (*(const f16x8*)(pqrow)) * SPLAT8(0.5f);
    f16x8 pqh1 = (*(const f16x8*)(pqrow + 32)) * SPLAT8(0.5f);

    f16x8 w3qA0  = *(const f16x8*)(w3q + g * 8);
    f16x8 w3qA1  = *(const f16x8*)(w3q + 32 + g * 8);
    f16x8 betaA0 = *(const f16x8*)(betaq + g * 8);
    f16x8 betaA1 = *(const f16x8*)(betaq + 32 + g * 8);

    const float clv = clvp[0];
    const f32x4 Z4 = {0.f, 0.f, 0.f, 0.f};

    const f16* pkbase = pk + ((size_t)b * SS + sb0 + r) * HID + g * 8;
    float* orow = out + (size_t)bt * SS + sb0;

    f16x8 kvA0, kvA1, kvB0, kvB1;
    f16x8 a0, a1;
    f32x4 acc[4];

    LOADKV(kvA0, kvA1, 0)
    LOADKV(kvB0, kvB1, 1)
    STAGE1(kvA0, kvA1)                // chunk 0 frags in a0,a1

    #pragma unroll
    for (int cc = 0; cc < 8; ++cc) {
        DOMFMA(acc)
        if (cc < 7) LOADKV(kvA0, kvA1, 2 * cc + 2)
        STAGE1(kvB0, kvB1)
        STAGE2(acc, 2 * cc)

        DOMFMA(acc)
        if (cc < 7) {
            LOADKV(kvB0, kvB1, 2 * cc + 3)
            STAGE1(kvA0, kvA1)
        }
        STAGE2(acc, 2 * cc + 1)
    }
}

extern "C" void kernel_launch(void* const* d_in, const int* in_sizes, int n_in,
                              void* d_out, int out_size, void* d_ws, size_t ws_size,
                              hipStream_t stream) {
    const float* h     = (const float*)d_in[0];
    const float* h_src = (const float*)d_in[1];
    const float* W1    = (const float*)d_in[2];
    const float* b1    = (const float*)d_in[3];
    const float* W2    = (const float*)d_in[4];
    const float* b2    = (const float*)d_in[5];
    const float* W3    = (const float*)d_in[6];
    const float* b3    = (const float*)d_in[7];
    float* out = (float*)d_out;

    f16* pq    = (f16*)d_ws;                     // B*T*HID f16
    f16* pk    = pq + (size_t)BB * TT * HID;     // B*S*HID f16
    f16* w2f   = pk + (size_t)BB * SS * HID;     // 4096 f16
    f16* w3q   = w2f + HID * HID;                // 64 f16
    f16* betaq = w3q + HID;                      // 64 f16
    float* clvp = (float*)(betaq + HID);         // 1 f32

    // TWO launches (cooperative fusion falsified R23; 3 launches falsified R21).
    setup_kernel<<<129, 128, 0, stream>>>(h, h_src, W1, b1, W2, b2, W3, b3,
                                          pq, pk, w2f, w3q, betaq, clvp);
    main_kernel<<<1024, 256, 0, stream>>>(pq, pk, w2f, w3q, betaq, clvp, out);
}